// Round 1
// baseline (595.129 us; speedup 1.0000x reference)
//
#include <hip/hip_runtime.h>
#include <math.h>

#define NTH 256

// (vr,vi) *= (c,s)
#define CMUL(vr, vi, c, s) { float _tr = (vr)*(c) - (vi)*(s); (vi) = (vr)*(s) + (vi)*(c); (vr) = _tr; }

// in-place FFT-4, natural order, W4 = -i
#define FFT4(r0,i0,r1,i1,r2,i2,r3,i3) {                     \
    float _acr=(r0)+(r2), _aci=(i0)+(i2);                   \
    float _scr=(r0)-(r2), _sci=(i0)-(i2);                   \
    float _bdr=(r1)+(r3), _bdi=(i1)+(i3);                   \
    float _sdr=(r1)-(r3), _sdi=(i1)-(i3);                   \
    (r0)=_acr+_bdr; (i0)=_aci+_bdi;                         \
    (r1)=_scr+_sdi; (i1)=_sci-_sdr;                         \
    (r2)=_acr-_bdr; (i2)=_aci-_bdi;                         \
    (r3)=_scr-_sdi; (i3)=_sci+_sdr; }

// FFT-16, natural input x[n]. OUTPUT DIGIT-SWAPPED: slot (4s+g) holds Y[s+4g].
__device__ __forceinline__ void fft16(float* xr, float* xi) {
    const float C1 = 0.92387953251128675613f;   // cos(pi/8)
    const float S1 = 0.38268343236508977172f;   // sin(pi/8)
    const float R2 = 0.70710678118654752440f;
#pragma unroll
    for (int q = 0; q < 4; ++q)
        FFT4(xr[q], xi[q], xr[4+q], xi[4+q], xr[8+q], xi[8+q], xr[12+q], xi[12+q]);
    CMUL(xr[5],  xi[5],   C1, -S1);                              // W^1
    CMUL(xr[9],  xi[9],   R2, -R2);                              // W^2
    CMUL(xr[13], xi[13],  S1, -C1);                              // W^3
    CMUL(xr[6],  xi[6],   R2, -R2);                              // W^2
    { float t = xr[10]; xr[10] = xi[10]; xi[10] = -t; }          // W^4 = -i
    CMUL(xr[14], xi[14], -R2, -R2);                              // W^6
    CMUL(xr[7],  xi[7],   S1, -C1);                              // W^3
    CMUL(xr[11], xi[11], -R2, -R2);                              // W^6
    CMUL(xr[15], xi[15], -C1,  S1);                              // W^9
#pragma unroll
    for (int s = 0; s < 4; ++s)
        FFT4(xr[4*s], xi[4*s], xr[4*s+1], xi[4*s+1], xr[4*s+2], xi[4*s+2], xr[4*s+3], xi[4*s+3]);
}

// One WAVE per row (4 rows / 256-thread block). T=2048. No __syncthreads anywhere:
// all LDS hazards are same-wave (DS ops execute in issue order per wave).
//
// LDS layout: 1024 floats per array (exactly 32 KiB/block -> 5 blocks/CU, was 4).
// Phase-1/2 swizzle: complex index e lives at physical slot e ^ (e>>6)  (bijective
// involution; hand-checked <=2-way banked on pack-write, r-read, stepA-read,
// stepB-write, stepC-read). Final (post-C3) layout is IDENTITY (stride-1 reads).
__global__ __launch_bounds__(NTH, 5)
void feat_kernel(const float* __restrict__ gx, float* __restrict__ gout) {
    const int tid = threadIdx.x;
    const int wv  = tid >> 6;
    const int ln  = tid & 63;
    const int row = blockIdx.x * 4 + wv;
    const float* xrow = gx + (size_t)row * 2048;

    __shared__ float ZRs[4][1024], ZIs[4][1024];
    float* Zr = ZRs[wv];
    float* Zi = ZIs[wv];

    const int al  = ln & 3;
    const int k2r = ln >> 2;          // == swizzle key (e>>6) for the 16-stride patterns
    const int b5  = ln >> 5;

    // ---- coalesced load; pack z[n]=x[2n]+i*x[2n+1] at swizzled slots ----
    const float4* x4 = (const float4*)xrow;
#pragma unroll
    for (int t = 0; t < 8; ++t) {
        float4 u = x4[ln + 64 * t];
        int c  = 2 * ln + 128 * t;            // even complex index
        int a0 = c ^ (2 * t + b5);            // SW(c): (c>>6) = 2t + b5 <= 15
        int a1 = a0 ^ 1;                      // SW(c+1)
        Zr[a0] = u.x; Zi[a0] = u.y;
        Zr[a1] = u.z; Zi[a1] = u.w;
    }

    // ---- contiguous 32 samples into regs: s[32*ln + 2j(+1)] = (Zr,Zi)[SW(16ln+j)] ----
    float r[32];
    {
        int base = 16 * ln;
#pragma unroll
        for (int j = 0; j < 16; ++j) {
            int a = base + (j ^ k2r);         // SW(16ln+j): XOR hits low4 (=j)
            r[2*j]   = Zr[a];
            r[2*j+1] = Zi[a];
        }
    }

    // ---- fused elementwise pass: max / min / sum / sum-of-squares ----
    float vmax = r[0], vmin = r[0], vsum = 0.0f, vsq = 0.0f;
#pragma unroll
    for (int e = 0; e < 32; ++e) {
        vmax = fmaxf(vmax, r[e]); vmin = fminf(vmin, r[e]);
        vsum += r[e]; vsq = fmaf(r[e], r[e], vsq);
    }
#pragma unroll
    for (int o = 1; o < 64; o <<= 1) {
        vmax = fmaxf(vmax, __shfl_xor(vmax, o, 64));
        vmin = fminf(vmin, __shfl_xor(vmin, o, 64));
        vsum += __shfl_xor(vsum, o, 64);
        vsq  += __shfl_xor(vsq,  o, 64);
    }
    float mx = vmax, mn = vmin, mean = vsum * (1.0f / 2048.0f);
    // var (ddof=1) from moments: Sum x^2 - Sum x * mean  (cancellation ~1e-5 << tol)
    float var = (vsq - vsum * mean) * (1.0f / 2047.0f);
    float sd  = sqrtf(var);

    // ---- peaks / valleys via compare bitwords (tie-exact, 2 cmps/elem) ----
    float lN = __shfl_up(r[31], 1, 64);     // lane-1's last elem (lane0: garbage, masked)
    unsigned aw = 0, bw = 0;                // bit m: a_i = s[i-1]<s[i], b_i = s[i-1]>s[i], i=32ln+m
#pragma unroll
    for (int m = 0; m < 32; ++m) {
        float l = (m == 0) ? lN : r[m - 1];
        float c = r[m];
        aw |= (unsigned)(l < c) << m;
        bw |= (unsigned)(l > c) << m;
    }
    unsigned an = __shfl_down(aw, 1, 64) & 1u;   // next lane's a at i=32ln+32
    unsigned bn = __shfl_down(bw, 1, 64) & 1u;
    unsigned pm = aw & ((bw >> 1) | (bn << 31)); // peak:   a_i & b_{i+1}
    unsigned vm = bw & ((aw >> 1) | (an << 31)); // valley: b_i & a_{i+1}
    if (ln == 0)  { pm &= ~1u; vm &= ~1u; }                  // exclude i=0
    if (ln == 63) { pm &= 0x7FFFFFFFu; vm &= 0x7FFFFFFFu; }  // exclude i=2047

    int pk = __popc(pm) | (__popc(vm) << 12);    // packed counts (each <= 2047 < 4096)
    int mp = pm ? 32 * ln + __ffs(pm) - 1 : (1 << 30);
    int mv = vm ? 32 * ln + __ffs(vm) - 1 : (1 << 30);
    int Mv = vm ? 32 * ln + 31 - __clz(vm) : -1;
#pragma unroll
    for (int o = 1; o < 64; o <<= 1) {
        pk += __shfl_xor(pk, o, 64);
        mp = min(mp, __shfl_xor(mp, o, 64));
        mv = min(mv, __shfl_xor(mv, o, 64));
        Mv = max(Mv, __shfl_xor(Mv, o, 64));
    }
    const int n_peaks = pk & 0xFFF, n_vals = pk >> 12, p0 = mp, v0 = mv, vlast = Mv;

    float PA = 0.0f, A2f = 0.0f, PH = 0.0f, A1f = 0.0f, PW = 0.0f;
    if (n_peaks >= 1 && n_vals >= 2) {     // wave-uniform
        // v1 = first valley strictly after v0
        int lo = v0 - 32 * ln;
        unsigned sel = (lo < 0) ? 0xFFFFFFFFu : ((lo >= 31) ? 0u : (0xFFFFFFFFu << (lo + 1)));
        unsigned m2 = vm & sel;
        int mv2 = m2 ? 32 * ln + __ffs(m2) - 1 : (1 << 30);
#pragma unroll
        for (int o = 1; o < 64; o <<= 1) mv2 = min(mv2, __shfl_xor(mv2, o, 64));
        const int v1 = mv2;

        // uniform broadcast reads from phase-1 layout
        auto sAt = [&](int p) -> float {
            int e = p >> 1;
            int a = e ^ (e >> 6);
            return (p & 1) ? Zi[a] : Zr[a];
        };
        float s_v0  = sAt(v0), s_p0 = sAt(p0);
        float s_pm1 = sAt(p0 - 1), s_v1m1 = sAt(v1 - 1), s_vLm1 = sAt(vlast - 1);
        PH = s_p0 - s_v0;
        float half = 0.5f * (s_p0 + s_v0);

        // telescoped trapz: trapz(a,b) = Sum_{i in [a,b-1]} s_i - 0.5*(s_a + s_{b-1})
        float S1 = 0.0f, S2 = 0.0f, S3 = 0.0f;
        int li = 1 << 30, ri = -1;
#pragma unroll
        for (int m = 0; m < 32; ++m) {
            int i = 32 * ln + m;
            float si = r[m];
            bool geV0 = (i >= v0), geP0 = (i >= p0);
            if (geV0 && !geP0)  S1 += si;            // [v0, p0-1]
            if (geP0 && i < v1) S2 += si;            // [p0, v1-1]
            if (geV0 && i < vlast) S3 += si;         // [v0, vlast-1]
            if (si >= half) {
                if (geV0 && !geP0)     li = min(li, i);
                if (i > v0 && i <= p0) ri = max(ri, i);
            }
        }
#pragma unroll
        for (int o = 1; o < 64; o <<= 1) {
            S1 += __shfl_xor(S1, o, 64);
            S2 += __shfl_xor(S2, o, 64);
            S3 += __shfl_xor(S3, o, 64);
            li = min(li, __shfl_xor(li, o, 64));
            ri = max(ri, __shfl_xor(ri, o, 64));
        }
        PA  = (S3 - 0.5f * (s_v0 + s_vLm1)) * (1.0f / 30.0f);
        // guards reproduce reference's empty-range -> 0 (possible with tie plateaus)
        A2f = (v1 > p0) ? (S2 - 0.5f * (s_p0 + s_v1m1)) * (1.0f / 30.0f) : 0.0f;
        A1f = (p0 > v0) ? (S1 - 0.5f * (s_v0 + s_pm1)) * (1.0f / 30.0f) : 0.0f;
        if (li == (1 << 30)) li = v0;
        if (ri < 0)          ri = p0;
        PW = (float)(ri - li) * (1.0f / 30.0f);
    }

    // ================= FFT-1024: Z[k2+16k1] via 16 x (16 x 4) =================
    // One sincos seeds ALL twiddle ladders (W2048^ln); everything else is 4-FMA rotations.
    float s0, c0;
    __sincosf((float)ln * (-3.14159265358979323846f / 1024.0f), &s0, &c0);

    // step A: per-lane FFT-16 over n2 of z[ln + 64*n2]
    float ar[16], ai[16];
#pragma unroll
    for (int n2 = 0; n2 < 16; ++n2) {
        int a = (ln ^ n2) + 64 * n2;          // SW(ln + 64*n2)
        ar[n2] = Zr[a];
        ai[n2] = Zi[a];
    }
    fft16(ar, ai);
    // step B: slot idx holds k2=(idx>>2)+4(idx&3) (involution); *= W1024^(ln*k2) via
    // recurrence with step W1024^ln = (W2048^ln)^2; write slot L=16ln+k2 at SW(L).
    {
        const float cb = c0 * c0 - s0 * s0;
        const float sb = 2.0f * c0 * s0;
        int wb = 16 * ln;
        Zr[wb + k2r] = ar[0];                 // k2=0: addr = wb + (0^k2r)
        Zi[wb + k2r] = ai[0];
        float cc = cb, ss = sb;
#pragma unroll
        for (int k2 = 1; k2 < 16; ++k2) {
            const int idx = (k2 >> 2) + 4 * (k2 & 3);
            CMUL(ar[idx], ai[idx], cc, ss);
            int a = wb + (k2 ^ k2r);
            Zr[a] = ar[idx];
            Zi[a] = ai[idx];
            float nc = cc * cb - ss * sb;     // advance to W1024^(ln*(k2+1))
            ss = cc * sb + ss * cb;
            cc = nc;
        }
    }
    // step C: lane' = al + 4*k2r gathers slots L = 16al + k2r + 64b at SW(L)
    {
        int cbase = 16 * al;
#pragma unroll
        for (int b = 0; b < 16; ++b) {
            int a = cbase + (k2r ^ b) + 64 * b;
            ar[b] = Zr[a];
            ai[b] = Zi[a];
        }
    }
    fft16(ar, ai);                            // slot 4s+g holds u[j], j = s+4g
    // C2: *= W64^(al*j) via recurrence; step W64^al from 4 constant pairs
    {
        float cA = (al & 1) ? 0.99518472667219688624f : 1.0f;
        float sA = (al & 1) ? -0.09801714032956060199f : 0.0f;
        float cB = (al & 1) ? 0.95694033573220886494f : 0.98078528040323044913f;
        float sB = (al & 1) ? -0.29028467725446236764f : -0.19509032201612826785f;
        float c1 = (al & 2) ? cB : cA;
        float s1 = (al & 2) ? sB : sA;
        float cc = c1, ss = s1;
#pragma unroll
        for (int j = 1; j < 16; ++j) {
            const int idx = (j >> 2) + 4 * (j & 3);
            CMUL(ar[idx], ai[idx], cc, ss);
            float nc = cc * c1 - ss * s1;
            ss = cc * s1 + ss * c1;
            cc = nc;
        }
    }
    // C3: FFT-4 over alpha (cross-lane); FINAL LAYOUT IDENTITY: Z[K] at addr K,
    // K = k2r + 16*j + 256*g
    {
        const bool hi = (al & 2) != 0;
        const bool b0 = (al & 1) != 0;
        const int g = ((al & 1) << 1) | (al >> 1);
        int fbase = k2r + 256 * g;
#pragma unroll
        for (int idx = 0; idx < 16; ++idx) {
            int j = (idx >> 2) + 4 * (idx & 3);
            float tr = __shfl_xor(ar[idx], 2, 64);
            float ti = __shfl_xor(ai[idx], 2, 64);
            float vr = hi ? (tr - ar[idx]) : (ar[idx] + tr);
            float vi = hi ? (ti - ai[idx]) : (ai[idx] + ti);
            float sr = __shfl_xor(vr, 1, 64);
            float si = __shfl_xor(vi, 1, 64);
            float Xr, Xi;
            if (!b0) { Xr = hi ? (vr + si) : (vr + sr); Xi = hi ? (vi - sr) : (vi + si); }
            else     { Xr = hi ? (sr - vi) : (sr - vr); Xi = hi ? (si + vr) : (si - vi); }
            Zr[fbase + 16 * j] = Xr;
            Zi[fbase + 16 * j] = Xi;
        }
    }

    // ---- real-split: sum |X[k]| over all 2048 bins; k=0..511 in loop (w=2 flat),
    //      k=0 overweight and k=512 fixed by exact lane-0 correction ----
    float amp = 0.0f;
    {
        float rc = c0, rs = s0;               // W2048^k at k = ln
        const float C16 = 0.98078528040323044913f, S16 = 0.19509032201612826785f;
#pragma unroll
        for (int t = 0; t < 8; ++t) {
            int k = ln + 64 * t;
            int m = (1024 - k) & 1023;
            float zr = Zr[k], zi = Zi[k];     // identity layout
            float mr = Zr[m], mi = Zi[m];
            float Er = 0.5f * (zr + mr), Ei = 0.5f * (zi - mi);
            float Or = 0.5f * (zi + mi), Oi = 0.5f * (mr - zr);
            float Pr = Or * rc - Oi * rs, Pi = Or * rs + Oi * rc;
            float x1r = Er + Pr, x1i = Ei + Pi;
            float x2r = Er - Pr, x2i = Ei - Pi;
            amp += 2.0f * (__builtin_amdgcn_sqrtf(x1r * x1r + x1i * x1i) +
                           __builtin_amdgcn_sqrtf(x2r * x2r + x2i * x2i));
            float nr = rc * C16 + rs * S16;   // rotate by W2048^64 = e^{-i*pi/16}
            rs = rs * C16 - rc * S16;
            rc = nr;
        }
        {
            float zr0 = Zr[0], zi0 = Zi[0];
            float q1 = zr0 + zi0, q2 = zr0 - zi0;
            // loop's k=0 term was exactly 2*(sqrt(q1^2)+sqrt(q2^2)); want weight 1
            float corr0 = __builtin_amdgcn_sqrtf(q1 * q1) + __builtin_amdgcn_sqrtf(q2 * q2);
            float zr5 = Zr[512], zi5 = Zi[512];
            float c512 = 2.0f * __builtin_amdgcn_sqrtf(zr5 * zr5 + zi5 * zi5);
            amp += (ln == 0) ? (c512 - corr0) : 0.0f;
        }
    }
#pragma unroll
    for (int o = 1; o < 64; o <<= 1) amp += __shfl_xor(amp, o, 64);
    float mean_amp = amp * (1.0f / 2048.0f);

    if (ln == 0) {
        float* o = gout + (size_t)row * 10;
        o[0] = mx;
        o[1] = mx - mn;
        o[2] = var;
        o[3] = sd;
        o[4] = mean_amp;
        o[5] = PA;
        o[6] = A2f;
        o[7] = PH;
        o[8] = A1f;
        o[9] = PW;
    }
}

extern "C" void kernel_launch(void* const* d_in, const int* in_sizes, int n_in,
                              void* d_out, int out_size, void* d_ws, size_t ws_size,
                              hipStream_t stream) {
    (void)d_ws; (void)ws_size; (void)n_in; (void)out_size;
    const float* x = (const float*)d_in[0];
    float* out = (float*)d_out;
    int rows = in_sizes[0] / 2048;           // 32768
    feat_kernel<<<dim3(rows / 4), dim3(NTH), 0, stream>>>(x, out);
}

// Round 4
// 398.786 us; speedup vs baseline: 1.4924x; 1.4924x over previous
//
#include <hip/hip_runtime.h>
#include <math.h>

#define NTH 256

// (vr,vi) *= (c,s)
#define CMUL(vr, vi, c, s) { float _tr = (vr)*(c) - (vi)*(s); (vi) = (vr)*(s) + (vi)*(c); (vr) = _tr; }

// in-place FFT-4, natural order, W4 = -i
#define FFT4(r0,i0,r1,i1,r2,i2,r3,i3) {                     \
    float _acr=(r0)+(r2), _aci=(i0)+(i2);                   \
    float _scr=(r0)-(r2), _sci=(i0)-(i2);                   \
    float _bdr=(r1)+(r3), _bdi=(i1)+(i3);                   \
    float _sdr=(r1)-(r3), _sdi=(i1)-(i3);                   \
    (r0)=_acr+_bdr; (i0)=_aci+_bdi;                         \
    (r1)=_scr+_sdi; (i1)=_sci-_sdr;                         \
    (r2)=_acr-_bdr; (i2)=_aci-_bdi;                         \
    (r3)=_scr-_sdi; (i3)=_sci+_sdr; }

// FFT-16, natural input x[n]. OUTPUT DIGIT-SWAPPED: slot (4s+g) holds Y[s+4g].
__device__ __forceinline__ void fft16(float* xr, float* xi) {
    const float C1 = 0.92387953251128675613f;   // cos(pi/8)
    const float S1 = 0.38268343236508977172f;   // sin(pi/8)
    const float R2 = 0.70710678118654752440f;
#pragma unroll
    for (int q = 0; q < 4; ++q)
        FFT4(xr[q], xi[q], xr[4+q], xi[4+q], xr[8+q], xi[8+q], xr[12+q], xi[12+q]);
    CMUL(xr[5],  xi[5],   C1, -S1);                              // W^1
    CMUL(xr[9],  xi[9],   R2, -R2);                              // W^2
    CMUL(xr[13], xi[13],  S1, -C1);                              // W^3
    CMUL(xr[6],  xi[6],   R2, -R2);                              // W^2
    { float t = xr[10]; xr[10] = xi[10]; xi[10] = -t; }          // W^4 = -i
    CMUL(xr[14], xi[14], -R2, -R2);                              // W^6
    CMUL(xr[7],  xi[7],   S1, -C1);                              // W^3
    CMUL(xr[11], xi[11], -R2, -R2);                              // W^6
    CMUL(xr[15], xi[15], -C1,  S1);                              // W^9
#pragma unroll
    for (int s = 0; s < 4; ++s)
        FFT4(xr[4*s], xi[4*s], xr[4*s+1], xi[4*s+1], xr[4*s+2], xi[4*s+2], xr[4*s+3], xi[4*s+3]);
}

// One WAVE per row (4 rows / 256-thread block). T=2048. No __syncthreads anywhere:
// all LDS hazards are same-wave (DS ops execute in issue order per wave).
//
// LDS layout: 1024 floats per array (exactly 32 KiB/block -> 5 blocks/CU possible
// if VGPR<=64). Phase-1/2 swizzle: complex index e lives at physical slot e^(e>>6)
// (bijective involution; <=2-way banked on pack-write, r-read, stepA-read,
// stepB-write, stepC-read). Final (post-C3) layout is IDENTITY (stride-1 reads).
//
// launch_bounds(256,4): DO NOT raise the 2nd arg to 5 — round-1 measured: the
// allocator squeezes 64->48 VGPRs and spills ~60 floats/thread to scratch
// (WRITE_SIZE 1.3MB -> 500MB, VALUBusy 86 -> 43, dur 162 -> 348 us).
__global__ __launch_bounds__(NTH, 4)
void feat_kernel(const float* __restrict__ gx, float* __restrict__ gout) {
    const int tid = threadIdx.x;
    const int wv  = tid >> 6;
    const int ln  = tid & 63;
    const int row = blockIdx.x * 4 + wv;
    const float* xrow = gx + (size_t)row * 2048;

    __shared__ float ZRs[4][1024], ZIs[4][1024];
    float* Zr = ZRs[wv];
    float* Zi = ZIs[wv];

    const int al  = ln & 3;
    const int k2r = ln >> 2;          // == swizzle key (e>>6) for the 16-stride patterns
    const int b5  = ln >> 5;

    // ---- coalesced load; pack z[n]=x[2n]+i*x[2n+1] at swizzled slots ----
    const float4* x4 = (const float4*)xrow;
#pragma unroll
    for (int t = 0; t < 8; ++t) {
        float4 u = x4[ln + 64 * t];
        int c  = 2 * ln + 128 * t;            // even complex index
        int a0 = c ^ (2 * t + b5);            // SW(c): (c>>6) = 2t + b5 <= 15
        int a1 = a0 ^ 1;                      // SW(c+1)
        Zr[a0] = u.x; Zi[a0] = u.y;
        Zr[a1] = u.z; Zi[a1] = u.w;
    }

    // ---- contiguous 32 samples into regs: s[32*ln + 2j(+1)] = (Zr,Zi)[SW(16ln+j)] ----
    float r[32];
    {
        int base = 16 * ln;
#pragma unroll
        for (int j = 0; j < 16; ++j) {
            int a = base + (j ^ k2r);         // SW(16ln+j): XOR hits low4 (=j)
            r[2*j]   = Zr[a];
            r[2*j+1] = Zi[a];
        }
    }

    // ---- fused elementwise pass: max / min / sum / sum-of-squares ----
    float vmax = r[0], vmin = r[0], vsum = 0.0f, vsq = 0.0f;
#pragma unroll
    for (int e = 0; e < 32; ++e) {
        vmax = fmaxf(vmax, r[e]); vmin = fminf(vmin, r[e]);
        vsum += r[e]; vsq = fmaf(r[e], r[e], vsq);
    }
#pragma unroll
    for (int o = 1; o < 64; o <<= 1) {
        vmax = fmaxf(vmax, __shfl_xor(vmax, o, 64));
        vmin = fminf(vmin, __shfl_xor(vmin, o, 64));
        vsum += __shfl_xor(vsum, o, 64);
        vsq  += __shfl_xor(vsq,  o, 64);
    }
    float mx = vmax, mn = vmin, mean = vsum * (1.0f / 2048.0f);
    // var (ddof=1) from moments: Sum x^2 - Sum x * mean  (cancellation ~1e-5 << tol)
    float var = (vsq - vsum * mean) * (1.0f / 2047.0f);
    float sd  = sqrtf(var);

    // ---- peaks / valleys via compare bitwords (tie-exact, 2 cmps/elem) ----
    float lN = __shfl_up(r[31], 1, 64);     // lane-1's last elem (lane0: garbage, masked)
    unsigned aw = 0, bw = 0;                // bit m: a_i = s[i-1]<s[i], b_i = s[i-1]>s[i], i=32ln+m
#pragma unroll
    for (int m = 0; m < 32; ++m) {
        float l = (m == 0) ? lN : r[m - 1];
        float c = r[m];
        aw |= (unsigned)(l < c) << m;
        bw |= (unsigned)(l > c) << m;
    }
    unsigned an = __shfl_down(aw, 1, 64) & 1u;   // next lane's a at i=32ln+32
    unsigned bn = __shfl_down(bw, 1, 64) & 1u;
    unsigned pm = aw & ((bw >> 1) | (bn << 31)); // peak:   a_i & b_{i+1}
    unsigned vm = bw & ((aw >> 1) | (an << 31)); // valley: b_i & a_{i+1}
    if (ln == 0)  { pm &= ~1u; vm &= ~1u; }                  // exclude i=0
    if (ln == 63) { pm &= 0x7FFFFFFFu; vm &= 0x7FFFFFFFu; }  // exclude i=2047

    int pk = __popc(pm) | (__popc(vm) << 12);    // packed counts (each <= 2047 < 4096)
    int mp = pm ? 32 * ln + __ffs(pm) - 1 : (1 << 30);
    int mv = vm ? 32 * ln + __ffs(vm) - 1 : (1 << 30);
    int Mv = vm ? 32 * ln + 31 - __clz(vm) : -1;
#pragma unroll
    for (int o = 1; o < 64; o <<= 1) {
        pk += __shfl_xor(pk, o, 64);
        mp = min(mp, __shfl_xor(mp, o, 64));
        mv = min(mv, __shfl_xor(mv, o, 64));
        Mv = max(Mv, __shfl_xor(Mv, o, 64));
    }
    const int n_peaks = pk & 0xFFF, n_vals = pk >> 12, p0 = mp, v0 = mv, vlast = Mv;

    float PA = 0.0f, A2f = 0.0f, PH = 0.0f, A1f = 0.0f, PW = 0.0f;
    if (n_peaks >= 1 && n_vals >= 2) {     // wave-uniform
        // v1 = first valley strictly after v0
        int lo = v0 - 32 * ln;
        unsigned sel = (lo < 0) ? 0xFFFFFFFFu : ((lo >= 31) ? 0u : (0xFFFFFFFFu << (lo + 1)));
        unsigned m2 = vm & sel;
        int mv2 = m2 ? 32 * ln + __ffs(m2) - 1 : (1 << 30);
#pragma unroll
        for (int o = 1; o < 64; o <<= 1) mv2 = min(mv2, __shfl_xor(mv2, o, 64));
        const int v1 = mv2;

        // uniform broadcast reads from phase-1 layout
        auto sAt = [&](int p) -> float {
            int e = p >> 1;
            int a = e ^ (e >> 6);
            return (p & 1) ? Zi[a] : Zr[a];
        };
        float s_v0  = sAt(v0), s_p0 = sAt(p0);
        float s_pm1 = sAt(p0 - 1), s_v1m1 = sAt(v1 - 1), s_vLm1 = sAt(vlast - 1);
        PH = s_p0 - s_v0;
        float half = 0.5f * (s_p0 + s_v0);

        // telescoped trapz: trapz(a,b) = Sum_{i in [a,b-1]} s_i - 0.5*(s_a + s_{b-1})
        float S1 = 0.0f, S2 = 0.0f, S3 = 0.0f;
        int li = 1 << 30, ri = -1;
#pragma unroll
        for (int m = 0; m < 32; ++m) {
            int i = 32 * ln + m;
            float si = r[m];
            bool geV0 = (i >= v0), geP0 = (i >= p0);
            if (geV0 && !geP0)  S1 += si;            // [v0, p0-1]
            if (geP0 && i < v1) S2 += si;            // [p0, v1-1]
            if (geV0 && i < vlast) S3 += si;         // [v0, vlast-1]
            if (si >= half) {
                if (geV0 && !geP0)     li = min(li, i);
                if (i > v0 && i <= p0) ri = max(ri, i);
            }
        }
#pragma unroll
        for (int o = 1; o < 64; o <<= 1) {
            S1 += __shfl_xor(S1, o, 64);
            S2 += __shfl_xor(S2, o, 64);
            S3 += __shfl_xor(S3, o, 64);
            li = min(li, __shfl_xor(li, o, 64));
            ri = max(ri, __shfl_xor(ri, o, 64));
        }
        PA  = (S3 - 0.5f * (s_v0 + s_vLm1)) * (1.0f / 30.0f);
        // guards reproduce reference's empty-range -> 0 (possible with tie plateaus)
        A2f = (v1 > p0) ? (S2 - 0.5f * (s_p0 + s_v1m1)) * (1.0f / 30.0f) : 0.0f;
        A1f = (p0 > v0) ? (S1 - 0.5f * (s_v0 + s_pm1)) * (1.0f / 30.0f) : 0.0f;
        if (li == (1 << 30)) li = v0;
        if (ri < 0)          ri = p0;
        PW = (float)(ri - li) * (1.0f / 30.0f);
    }

    // ================= FFT-1024: Z[k2+16k1] via 16 x (16 x 4) =================
    // One sincos seeds ALL twiddle ladders (W2048^ln); everything else is 4-FMA rotations.
    float s0, c0;
    __sincosf((float)ln * (-3.14159265358979323846f / 1024.0f), &s0, &c0);

    // step A: per-lane FFT-16 over n2 of z[ln + 64*n2]
    float ar[16], ai[16];
#pragma unroll
    for (int n2 = 0; n2 < 16; ++n2) {
        int a = (ln ^ n2) + 64 * n2;          // SW(ln + 64*n2)
        ar[n2] = Zr[a];
        ai[n2] = Zi[a];
    }
    fft16(ar, ai);
    // step B: slot idx holds k2=(idx>>2)+4(idx&3) (involution); *= W1024^(ln*k2) via
    // recurrence with step W1024^ln = (W2048^ln)^2; write slot L=16ln+k2 at SW(L).
    {
        const float cb = c0 * c0 - s0 * s0;
        const float sb = 2.0f * c0 * s0;
        int wb = 16 * ln;
        Zr[wb + k2r] = ar[0];                 // k2=0: addr = wb + (0^k2r)
        Zi[wb + k2r] = ai[0];
        float cc = cb, ss = sb;
#pragma unroll
        for (int k2 = 1; k2 < 16; ++k2) {
            const int idx = (k2 >> 2) + 4 * (k2 & 3);
            CMUL(ar[idx], ai[idx], cc, ss);
            int a = wb + (k2 ^ k2r);
            Zr[a] = ar[idx];
            Zi[a] = ai[idx];
            float nc = cc * cb - ss * sb;     // advance to W1024^(ln*(k2+1))
            ss = cc * sb + ss * cb;
            cc = nc;
        }
    }
    // step C: lane' = al + 4*k2r gathers slots L = 16al + k2r + 64b at SW(L)
    {
        int cbase = 16 * al;
#pragma unroll
        for (int b = 0; b < 16; ++b) {
            int a = cbase + (k2r ^ b) + 64 * b;
            ar[b] = Zr[a];
            ai[b] = Zi[a];
        }
    }
    fft16(ar, ai);                            // slot 4s+g holds u[j], j = s+4g
    // C2: *= W64^(al*j) via recurrence; step W64^al from 4 constant pairs
    {
        float cA = (al & 1) ? 0.99518472667219688624f : 1.0f;
        float sA = (al & 1) ? -0.09801714032956060199f : 0.0f;
        float cB = (al & 1) ? 0.95694033573220886494f : 0.98078528040323044913f;
        float sB = (al & 1) ? -0.29028467725446236764f : -0.19509032201612826785f;
        float c1 = (al & 2) ? cB : cA;
        float s1 = (al & 2) ? sB : sA;
        float cc = c1, ss = s1;
#pragma unroll
        for (int j = 1; j < 16; ++j) {
            const int idx = (j >> 2) + 4 * (j & 3);
            CMUL(ar[idx], ai[idx], cc, ss);
            float nc = cc * c1 - ss * s1;
            ss = cc * s1 + ss * c1;
            cc = nc;
        }
    }
    // C3: FFT-4 over alpha (cross-lane); FINAL LAYOUT IDENTITY: Z[K] at addr K,
    // K = k2r + 16*j + 256*g
    {
        const bool hi = (al & 2) != 0;
        const bool b0 = (al & 1) != 0;
        const int g = ((al & 1) << 1) | (al >> 1);
        int fbase = k2r + 256 * g;
#pragma unroll
        for (int idx = 0; idx < 16; ++idx) {
            int j = (idx >> 2) + 4 * (idx & 3);
            float tr = __shfl_xor(ar[idx], 2, 64);
            float ti = __shfl_xor(ai[idx], 2, 64);
            float vr = hi ? (tr - ar[idx]) : (ar[idx] + tr);
            float vi = hi ? (ti - ai[idx]) : (ai[idx] + ti);
            float sr = __shfl_xor(vr, 1, 64);
            float si = __shfl_xor(vi, 1, 64);
            float Xr, Xi;
            if (!b0) { Xr = hi ? (vr + si) : (vr + sr); Xi = hi ? (vi - sr) : (vi + si); }
            else     { Xr = hi ? (sr - vi) : (sr - vr); Xi = hi ? (si + vr) : (si - vi); }
            Zr[fbase + 16 * j] = Xr;
            Zi[fbase + 16 * j] = Xi;
        }
    }

    // ---- real-split: sum |X[k]| over all 2048 bins; k=0..511 in loop (w=2 flat),
    //      k=0 overweight and k=512 fixed by exact lane-0 correction ----
    float amp = 0.0f;
    {
        float rc = c0, rs = s0;               // W2048^k at k = ln
        const float C16 = 0.98078528040323044913f, S16 = 0.19509032201612826785f;
#pragma unroll
        for (int t = 0; t < 8; ++t) {
            int k = ln + 64 * t;
            int m = (1024 - k) & 1023;
            float zr = Zr[k], zi = Zi[k];     // identity layout
            float mr = Zr[m], mi = Zi[m];
            float Er = 0.5f * (zr + mr), Ei = 0.5f * (zi - mi);
            float Or = 0.5f * (zi + mi), Oi = 0.5f * (mr - zr);
            float Pr = Or * rc - Oi * rs, Pi = Or * rs + Oi * rc;
            float x1r = Er + Pr, x1i = Ei + Pi;
            float x2r = Er - Pr, x2i = Ei - Pi;
            amp += 2.0f * (__builtin_amdgcn_sqrtf(x1r * x1r + x1i * x1i) +
                           __builtin_amdgcn_sqrtf(x2r * x2r + x2i * x2i));
            float nr = rc * C16 + rs * S16;   // rotate by W2048^64 = e^{-i*pi/16}
            rs = rs * C16 - rc * S16;
            rc = nr;
        }
        {
            float zr0 = Zr[0], zi0 = Zi[0];
            float q1 = zr0 + zi0, q2 = zr0 - zi0;
            // loop's k=0 term was exactly 2*(sqrt(q1^2)+sqrt(q2^2)); want weight 1
            float corr0 = __builtin_amdgcn_sqrtf(q1 * q1) + __builtin_amdgcn_sqrtf(q2 * q2);
            float zr5 = Zr[512], zi5 = Zi[512];
            float c512 = 2.0f * __builtin_amdgcn_sqrtf(zr5 * zr5 + zi5 * zi5);
            amp += (ln == 0) ? (c512 - corr0) : 0.0f;
        }
    }
#pragma unroll
    for (int o = 1; o < 64; o <<= 1) amp += __shfl_xor(amp, o, 64);
    float mean_amp = amp * (1.0f / 2048.0f);

    if (ln == 0) {
        float* o = gout + (size_t)row * 10;
        o[0] = mx;
        o[1] = mx - mn;
        o[2] = var;
        o[3] = sd;
        o[4] = mean_amp;
        o[5] = PA;
        o[6] = A2f;
        o[7] = PH;
        o[8] = A1f;
        o[9] = PW;
    }
}

extern "C" void kernel_launch(void* const* d_in, const int* in_sizes, int n_in,
                              void* d_out, int out_size, void* d_ws, size_t ws_size,
                              hipStream_t stream) {
    (void)d_ws; (void)ws_size; (void)n_in; (void)out_size;
    const float* x = (const float*)d_in[0];
    float* out = (float*)d_out;
    int rows = in_sizes[0] / 2048;           // 32768
    feat_kernel<<<dim3(rows / 4), dim3(NTH), 0, stream>>>(x, out);
}

// Round 5
// 394.945 us; speedup vs baseline: 1.5069x; 1.0097x over previous
//
#include <hip/hip_runtime.h>
#include <math.h>

#define NTH 256

// (vr,vi) *= (c,s)
#define CMUL(vr, vi, c, s) { float _tr = (vr)*(c) - (vi)*(s); (vi) = (vr)*(s) + (vi)*(c); (vr) = _tr; }

// in-place FFT-4, natural order, W4 = -i
#define FFT4(r0,i0,r1,i1,r2,i2,r3,i3) {                     \
    float _acr=(r0)+(r2), _aci=(i0)+(i2);                   \
    float _scr=(r0)-(r2), _sci=(i0)-(i2);                   \
    float _bdr=(r1)+(r3), _bdi=(i1)+(i3);                   \
    float _sdr=(r1)-(r3), _sdi=(i1)-(i3);                   \
    (r0)=_acr+_bdr; (i0)=_aci+_bdi;                         \
    (r1)=_scr+_sdi; (i1)=_sci-_sdr;                         \
    (r2)=_acr-_bdr; (i2)=_aci-_bdi;                         \
    (r3)=_scr-_sdi; (i3)=_sci+_sdr; }

// FFT-16, natural input x[n]. OUTPUT DIGIT-SWAPPED: slot (4s+g) holds Y[s+4g].
__device__ __forceinline__ void fft16(float* xr, float* xi) {
    const float C1 = 0.92387953251128675613f;   // cos(pi/8)
    const float S1 = 0.38268343236508977172f;   // sin(pi/8)
    const float R2 = 0.70710678118654752440f;
#pragma unroll
    for (int q = 0; q < 4; ++q)
        FFT4(xr[q], xi[q], xr[4+q], xi[4+q], xr[8+q], xi[8+q], xr[12+q], xi[12+q]);
    CMUL(xr[5],  xi[5],   C1, -S1);                              // W^1
    CMUL(xr[9],  xi[9],   R2, -R2);                              // W^2
    CMUL(xr[13], xi[13],  S1, -C1);                              // W^3
    CMUL(xr[6],  xi[6],   R2, -R2);                              // W^2
    { float t = xr[10]; xr[10] = xi[10]; xi[10] = -t; }          // W^4 = -i
    CMUL(xr[14], xi[14], -R2, -R2);                              // W^6
    CMUL(xr[7],  xi[7],   S1, -C1);                              // W^3
    CMUL(xr[11], xi[11], -R2, -R2);                              // W^6
    CMUL(xr[15], xi[15], -C1,  S1);                              // W^9
#pragma unroll
    for (int s = 0; s < 4; ++s)
        FFT4(xr[4*s], xi[4*s], xr[4*s+1], xi[4*s+1], xr[4*s+2], xi[4*s+2], xr[4*s+3], xi[4*s+3]);
}

// One WAVE per row (4 rows / 256-thread block). T=2048. No __syncthreads anywhere:
// all LDS hazards are same-wave (DS ops execute in issue order per wave).
//
// LDS layout: 1024 floats per array (32 KiB/block -> 5 blocks/CU if VGPR<=102).
// Phase-1/2 swizzle: complex index e lives at physical slot e^(e>>6) (bijective
// involution; <=2-way banked on pack-write, r-read, stepA-read, stepB-write,
// stepC-read). Final (post-C3) layout is IDENTITY (stride-1 reads).
//
// VGPR budget history (measured): the backend maps launch_bounds' 2nd arg to a
// VGPR cap of ~256/min_waves: (256,5)->48 VGPR (~60 spilled dwords/thread,
// WRITE 500MB, 348us); (256,4)->64 VGPR (7 spilled dwords/thread, WRITE 58.6MB,
// 197us). (256,2) -> cap ~128: fits the ~72-90 live regs without spill;
// occupancy stays LDS-capped (5 blocks/CU = 20 waves) for any VGPR<=102.
__global__ __launch_bounds__(NTH, 2)
void feat_kernel(const float* __restrict__ gx, float* __restrict__ gout) {
    const int tid = threadIdx.x;
    const int wv  = tid >> 6;
    const int ln  = tid & 63;
    const int row = blockIdx.x * 4 + wv;
    const float* xrow = gx + (size_t)row * 2048;
    float* orow = gout + (size_t)row * 10;

    __shared__ float ZRs[4][1024], ZIs[4][1024];
    float* Zr = ZRs[wv];
    float* Zi = ZIs[wv];

    const int al  = ln & 3;
    const int k2r = ln >> 2;          // == swizzle key (e>>6) for the 16-stride patterns
    const int b5  = ln >> 5;

    // ---- coalesced load; pack z[n]=x[2n]+i*x[2n+1] at swizzled slots ----
    const float4* x4 = (const float4*)xrow;
#pragma unroll
    for (int t = 0; t < 8; ++t) {
        float4 u = x4[ln + 64 * t];
        int c  = 2 * ln + 128 * t;            // even complex index
        int a0 = c ^ (2 * t + b5);            // SW(c): (c>>6) = 2t + b5 <= 15
        int a1 = a0 ^ 1;                      // SW(c+1)
        Zr[a0] = u.x; Zi[a0] = u.y;
        Zr[a1] = u.z; Zi[a1] = u.w;
    }

    // ---- contiguous 32 samples into regs: s[32*ln + 2j(+1)] = (Zr,Zi)[SW(16ln+j)] ----
    float r[32];
    {
        int base = 16 * ln;
#pragma unroll
        for (int j = 0; j < 16; ++j) {
            int a = base + (j ^ k2r);         // SW(16ln+j): XOR hits low4 (=j)
            r[2*j]   = Zr[a];
            r[2*j+1] = Zi[a];
        }
    }

    // ---- fused elementwise pass: max / min / sum / sum-of-squares ----
    float vmax = r[0], vmin = r[0], vsum = 0.0f, vsq = 0.0f;
#pragma unroll
    for (int e = 0; e < 32; ++e) {
        vmax = fmaxf(vmax, r[e]); vmin = fminf(vmin, r[e]);
        vsum += r[e]; vsq = fmaf(r[e], r[e], vsq);
    }
#pragma unroll
    for (int o = 1; o < 64; o <<= 1) {
        vmax = fmaxf(vmax, __shfl_xor(vmax, o, 64));
        vmin = fminf(vmin, __shfl_xor(vmin, o, 64));
        vsum += __shfl_xor(vsum, o, 64);
        vsq  += __shfl_xor(vsq,  o, 64);
    }
    {
        float mean = vsum * (1.0f / 2048.0f);
        // var (ddof=1) from moments: Sum x^2 - Sum x * mean (cancellation ~1e-5 << tol)
        float var = (vsq - vsum * mean) * (1.0f / 2047.0f);
        // EARLY STORE of stats: kills 4 live regs across the FFT section
        if (ln == 0) {
            orow[0] = vmax;
            orow[1] = vmax - vmin;
            orow[2] = var;
            orow[3] = sqrtf(var);
        }
    }

    // ---- peaks / valleys via compare bitwords (tie-exact, 2 cmps/elem) ----
    float lN = __shfl_up(r[31], 1, 64);     // lane-1's last elem (lane0: garbage, masked)
    unsigned aw = 0, bw = 0;                // bit m: a_i = s[i-1]<s[i], b_i = s[i-1]>s[i], i=32ln+m
#pragma unroll
    for (int m = 0; m < 32; ++m) {
        float l = (m == 0) ? lN : r[m - 1];
        float c = r[m];
        aw |= (unsigned)(l < c) << m;
        bw |= (unsigned)(l > c) << m;
    }
    unsigned an = __shfl_down(aw, 1, 64) & 1u;   // next lane's a at i=32ln+32
    unsigned bn = __shfl_down(bw, 1, 64) & 1u;
    unsigned pm = aw & ((bw >> 1) | (bn << 31)); // peak:   a_i & b_{i+1}
    unsigned vm = bw & ((aw >> 1) | (an << 31)); // valley: b_i & a_{i+1}
    if (ln == 0)  { pm &= ~1u; vm &= ~1u; }                  // exclude i=0
    if (ln == 63) { pm &= 0x7FFFFFFFu; vm &= 0x7FFFFFFFu; }  // exclude i=2047

    int pk = __popc(pm) | (__popc(vm) << 12);    // packed counts (each <= 2047 < 4096)
    int mp = pm ? 32 * ln + __ffs(pm) - 1 : (1 << 30);
    int mv = vm ? 32 * ln + __ffs(vm) - 1 : (1 << 30);
    int Mv = vm ? 32 * ln + 31 - __clz(vm) : -1;
#pragma unroll
    for (int o = 1; o < 64; o <<= 1) {
        pk += __shfl_xor(pk, o, 64);
        mp = min(mp, __shfl_xor(mp, o, 64));
        mv = min(mv, __shfl_xor(mv, o, 64));
        Mv = max(Mv, __shfl_xor(Mv, o, 64));
    }
    const int n_peaks = pk & 0xFFF, n_vals = pk >> 12, p0 = mp, v0 = mv, vlast = Mv;

    {
        float PA = 0.0f, A2f = 0.0f, PH = 0.0f, A1f = 0.0f, PW = 0.0f;
        if (n_peaks >= 1 && n_vals >= 2) {     // wave-uniform
            // v1 = first valley strictly after v0
            int lo = v0 - 32 * ln;
            unsigned sel = (lo < 0) ? 0xFFFFFFFFu : ((lo >= 31) ? 0u : (0xFFFFFFFFu << (lo + 1)));
            unsigned m2 = vm & sel;
            int mv2 = m2 ? 32 * ln + __ffs(m2) - 1 : (1 << 30);
#pragma unroll
            for (int o = 1; o < 64; o <<= 1) mv2 = min(mv2, __shfl_xor(mv2, o, 64));
            const int v1 = mv2;

            // uniform broadcast reads from phase-1 layout
            auto sAt = [&](int p) -> float {
                int e = p >> 1;
                int a = e ^ (e >> 6);
                return (p & 1) ? Zi[a] : Zr[a];
            };
            float s_v0  = sAt(v0), s_p0 = sAt(p0);
            float s_pm1 = sAt(p0 - 1), s_v1m1 = sAt(v1 - 1), s_vLm1 = sAt(vlast - 1);
            PH = s_p0 - s_v0;
            float half = 0.5f * (s_p0 + s_v0);

            // telescoped trapz: trapz(a,b) = Sum_{i in [a,b-1]} s_i - 0.5*(s_a + s_{b-1})
            float S1 = 0.0f, S2 = 0.0f, S3 = 0.0f;
            int li = 1 << 30, ri = -1;
#pragma unroll
            for (int m = 0; m < 32; ++m) {
                int i = 32 * ln + m;
                float si = r[m];
                bool geV0 = (i >= v0), geP0 = (i >= p0);
                if (geV0 && !geP0)  S1 += si;            // [v0, p0-1]
                if (geP0 && i < v1) S2 += si;            // [p0, v1-1]
                if (geV0 && i < vlast) S3 += si;         // [v0, vlast-1]
                if (si >= half) {
                    if (geV0 && !geP0)     li = min(li, i);
                    if (i > v0 && i <= p0) ri = max(ri, i);
                }
            }
#pragma unroll
            for (int o = 1; o < 64; o <<= 1) {
                S1 += __shfl_xor(S1, o, 64);
                S2 += __shfl_xor(S2, o, 64);
                S3 += __shfl_xor(S3, o, 64);
                li = min(li, __shfl_xor(li, o, 64));
                ri = max(ri, __shfl_xor(ri, o, 64));
            }
            PA  = (S3 - 0.5f * (s_v0 + s_vLm1)) * (1.0f / 30.0f);
            // guards reproduce reference's empty-range -> 0 (possible with tie plateaus)
            A2f = (v1 > p0) ? (S2 - 0.5f * (s_p0 + s_v1m1)) * (1.0f / 30.0f) : 0.0f;
            A1f = (p0 > v0) ? (S1 - 0.5f * (s_v0 + s_pm1)) * (1.0f / 30.0f) : 0.0f;
            if (li == (1 << 30)) li = v0;
            if (ri < 0)          ri = p0;
            PW = (float)(ri - li) * (1.0f / 30.0f);
        }
        // EARLY STORE of ippg block (zeros when guard fails — matches reference):
        // kills 5 live regs across the FFT + amplitude section.
        if (ln == 0) {
            orow[5] = PA;
            orow[6] = A2f;
            orow[7] = PH;
            orow[8] = A1f;
            orow[9] = PW;
        }
    }

    // ================= FFT-1024: Z[k2+16k1] via 16 x (16 x 4) =================
    // One sincos seeds ALL twiddle ladders (W2048^ln); everything else is 4-FMA rotations.
    float s0, c0;
    __sincosf((float)ln * (-3.14159265358979323846f / 1024.0f), &s0, &c0);

    // step A: per-lane FFT-16 over n2 of z[ln + 64*n2]
    float ar[16], ai[16];
#pragma unroll
    for (int n2 = 0; n2 < 16; ++n2) {
        int a = (ln ^ n2) + 64 * n2;          // SW(ln + 64*n2)
        ar[n2] = Zr[a];
        ai[n2] = Zi[a];
    }
    fft16(ar, ai);
    // step B: slot idx holds k2=(idx>>2)+4(idx&3) (involution); *= W1024^(ln*k2) via
    // recurrence with step W1024^ln = (W2048^ln)^2; write slot L=16ln+k2 at SW(L).
    {
        const float cb = c0 * c0 - s0 * s0;
        const float sb = 2.0f * c0 * s0;
        int wb = 16 * ln;
        Zr[wb + k2r] = ar[0];                 // k2=0: addr = wb + (0^k2r)
        Zi[wb + k2r] = ai[0];
        float cc = cb, ss = sb;
#pragma unroll
        for (int k2 = 1; k2 < 16; ++k2) {
            const int idx = (k2 >> 2) + 4 * (k2 & 3);
            CMUL(ar[idx], ai[idx], cc, ss);
            int a = wb + (k2 ^ k2r);
            Zr[a] = ar[idx];
            Zi[a] = ai[idx];
            float nc = cc * cb - ss * sb;     // advance to W1024^(ln*(k2+1))
            ss = cc * sb + ss * cb;
            cc = nc;
        }
    }
    // step C: lane' = al + 4*k2r gathers slots L = 16al + k2r + 64b at SW(L)
    {
        int cbase = 16 * al;
#pragma unroll
        for (int b = 0; b < 16; ++b) {
            int a = cbase + (k2r ^ b) + 64 * b;
            ar[b] = Zr[a];
            ai[b] = Zi[a];
        }
    }
    fft16(ar, ai);                            // slot 4s+g holds u[j], j = s+4g
    // C2: *= W64^(al*j) via recurrence; step W64^al from 4 constant pairs
    {
        float cA = (al & 1) ? 0.99518472667219688624f : 1.0f;
        float sA = (al & 1) ? -0.09801714032956060199f : 0.0f;
        float cB = (al & 1) ? 0.95694033573220886494f : 0.98078528040323044913f;
        float sB = (al & 1) ? -0.29028467725446236764f : -0.19509032201612826785f;
        float c1 = (al & 2) ? cB : cA;
        float s1 = (al & 2) ? sB : sA;
        float cc = c1, ss = s1;
#pragma unroll
        for (int j = 1; j < 16; ++j) {
            const int idx = (j >> 2) + 4 * (j & 3);
            CMUL(ar[idx], ai[idx], cc, ss);
            float nc = cc * c1 - ss * s1;
            ss = cc * s1 + ss * c1;
            cc = nc;
        }
    }
    // C3: FFT-4 over alpha (cross-lane); FINAL LAYOUT IDENTITY: Z[K] at addr K,
    // K = k2r + 16*j + 256*g
    {
        const bool hi = (al & 2) != 0;
        const bool b0 = (al & 1) != 0;
        const int g = ((al & 1) << 1) | (al >> 1);
        int fbase = k2r + 256 * g;
#pragma unroll
        for (int idx = 0; idx < 16; ++idx) {
            int j = (idx >> 2) + 4 * (idx & 3);
            float tr = __shfl_xor(ar[idx], 2, 64);
            float ti = __shfl_xor(ai[idx], 2, 64);
            float vr = hi ? (tr - ar[idx]) : (ar[idx] + tr);
            float vi = hi ? (ti - ai[idx]) : (ai[idx] + ti);
            float sr = __shfl_xor(vr, 1, 64);
            float si = __shfl_xor(vi, 1, 64);
            float Xr, Xi;
            if (!b0) { Xr = hi ? (vr + si) : (vr + sr); Xi = hi ? (vi - sr) : (vi + si); }
            else     { Xr = hi ? (sr - vi) : (sr - vr); Xi = hi ? (si + vr) : (si - vi); }
            Zr[fbase + 16 * j] = Xr;
            Zi[fbase + 16 * j] = Xi;
        }
    }

    // ---- real-split: sum |X[k]| over all 2048 bins; k=0..511 in loop (w=2 flat),
    //      k=0 overweight and k=512 fixed by exact lane-0 correction ----
    float amp = 0.0f;
    {
        float rc = c0, rs = s0;               // W2048^k at k = ln
        const float C16 = 0.98078528040323044913f, S16 = 0.19509032201612826785f;
#pragma unroll
        for (int t = 0; t < 8; ++t) {
            int k = ln + 64 * t;
            int m = (1024 - k) & 1023;
            float zr = Zr[k], zi = Zi[k];     // identity layout
            float mr = Zr[m], mi = Zi[m];
            float Er = 0.5f * (zr + mr), Ei = 0.5f * (zi - mi);
            float Or = 0.5f * (zi + mi), Oi = 0.5f * (mr - zr);
            float Pr = Or * rc - Oi * rs, Pi = Or * rs + Oi * rc;
            float x1r = Er + Pr, x1i = Ei + Pi;
            float x2r = Er - Pr, x2i = Ei - Pi;
            amp += 2.0f * (__builtin_amdgcn_sqrtf(x1r * x1r + x1i * x1i) +
                           __builtin_amdgcn_sqrtf(x2r * x2r + x2i * x2i));
            float nr = rc * C16 + rs * S16;   // rotate by W2048^64 = e^{-i*pi/16}
            rs = rs * C16 - rc * S16;
            rc = nr;
        }
        {
            float zr0 = Zr[0], zi0 = Zi[0];
            float q1 = zr0 + zi0, q2 = zr0 - zi0;
            // loop's k=0 term was exactly 2*(sqrt(q1^2)+sqrt(q2^2)); want weight 1
            float corr0 = __builtin_amdgcn_sqrtf(q1 * q1) + __builtin_amdgcn_sqrtf(q2 * q2);
            float zr5 = Zr[512], zi5 = Zi[512];
            float c512 = 2.0f * __builtin_amdgcn_sqrtf(zr5 * zr5 + zi5 * zi5);
            amp += (ln == 0) ? (c512 - corr0) : 0.0f;
        }
    }
#pragma unroll
    for (int o = 1; o < 64; o <<= 1) amp += __shfl_xor(amp, o, 64);

    if (ln == 0) {
        orow[4] = amp * (1.0f / 2048.0f);
    }
}

extern "C" void kernel_launch(void* const* d_in, const int* in_sizes, int n_in,
                              void* d_out, int out_size, void* d_ws, size_t ws_size,
                              hipStream_t stream) {
    (void)d_ws; (void)ws_size; (void)n_in; (void)out_size;
    const float* x = (const float*)d_in[0];
    float* out = (float*)d_out;
    int rows = in_sizes[0] / 2048;           // 32768
    feat_kernel<<<dim3(rows / 4), dim3(NTH), 0, stream>>>(x, out);
}